// Round 8
// baseline (322.324 us; speedup 1.0000x reference)
//
#include <hip/hip_runtime.h>
#include <stdint.h>

// S3FD anchor assignment — spatially-binned exact rewrite.
// d_in[0]: anchor [N,4] f32, d_in[1]: gt [M,4] f32. d_out: assign [N] int32.
//
// Round 7 post-mortem: fused brute-force kernel hit VALUBusy 90% at 147 us —
// VALU-bound on 1e8 IoU evals (~42% of instrs = IEEE v_div sequences) though
// ~96% of pairs never intersect. Round 8: bin anchors by center into 32x32
// cells of 32 px. Overlap requires anchor center inside gt expanded by
// 64.5 px (max anchor half-extent < 64, + fp slack), so:
//   k_assign: each anchor tests only GTs listed for its cell   (~17 vs 200)
//   k_top3:   each GT block scans only anchors in its cells    (~1e7 vs 1e8)
// Culled pairs have iou == 0 exactly; argmax unaffected (zero keys lose),
// top-3 zero-fill reproduced by seeding keys (0,~0),(0,~1),(0,~2).
// All merges are order-independent key-maxes -> deterministic output even
// though atomic scatter order is not.
//
// Key encoding (exact jax semantics), per-GT top-3:
//   key = (iou_bits << 32) | ~anchor_idx    (stable top_k: higher iou, then
//                                            lower anchor index wins)

typedef unsigned int u32;
typedef unsigned short u16;
typedef unsigned long long u64;

#define POS_THRESH 0.5f
#define NEG_THRESH 0.3f
#define CLAIM_THRESH 0.1f

constexpr int NCX = 32, NCY = 32, NCELL = NCX * NCY;  // 32x32 cells, 32 px
constexpr float INV_CELL = 0.03125f;                  // 1/32
constexpr float MARGIN = 64.5f;   // max anchor half-extent (<64.001) + slack
constexpr int MPAD = 256;         // padded GT count (M = 200)

#define INS3(t0, t1, t2, k) do {                                  \
    if ((k) > (t2)) {                                             \
        if ((k) > (t0))      { t2 = t1; t1 = t0; t0 = (k); }      \
        else if ((k) > (t1)) { t2 = t1; t1 = (k); }               \
        else                 { t2 = (k); }                        \
    } } while (0)

// IoU expression verbatim from the passing rounds (numpy-exact).
#define IOU_EVAL(a, areaA, g, areaG, inter, iou) {                \
    float ltx = fmaxf(a.x, g.x), lty = fmaxf(a.y, g.y);           \
    float rbx = fminf(a.z, g.z), rby = fminf(a.w, g.w);           \
    float ww = fmaxf(rbx - ltx, 0.0f);                            \
    float hh = fmaxf(rby - lty, 0.0f);                            \
    inter = ww * hh;                                              \
    iou = 0.0f;                                                   \
    if (inter > 0.0f) iou = inter / ((areaA + areaG) - inter);    \
}

__device__ __forceinline__ u64 shfl_xor_u64(u64 x, int mask) {
    int lo = __shfl_xor((int)(u32)x, mask, 64);
    int hi = __shfl_xor((int)(u32)(x >> 32), mask, 64);
    return ((u64)(u32)hi << 32) | (u32)lo;
}

__device__ __forceinline__ int cell_of(const float4 a) {
    float cx = 0.5f * (a.x + a.z);
    float cy = 0.5f * (a.y + a.w);
    int ix = (int)(cx * INV_CELL);
    int iy = (int)(cy * INV_CELL);
    ix = ix < 0 ? 0 : (ix > NCX - 1 ? NCX - 1 : ix);
    iy = iy < 0 ? 0 : (iy > NCY - 1 ? NCY - 1 : iy);
    return iy * NCX + ix;
}

__device__ __forceinline__ void gt_range(const float4 g, int& clx, int& chx,
                                         int& cly, int& chy) {
    clx = (int)floorf((g.x - MARGIN) * INV_CELL);
    chx = (int)floorf((g.z + MARGIN) * INV_CELL);
    cly = (int)floorf((g.y - MARGIN) * INV_CELL);
    chy = (int)floorf((g.w + MARGIN) * INV_CELL);
    clx = clx < 0 ? 0 : (clx > NCX - 1 ? NCX - 1 : clx);
    chx = chx < 0 ? 0 : (chx > NCX - 1 ? NCX - 1 : chx);
    cly = cly < 0 ? 0 : (cly > NCY - 1 ? NCY - 1 : cly);
    chy = chy < 0 ? 0 : (chy > NCY - 1 ? NCY - 1 : chy);
}

// ---------------------------------------------------------------------------
__global__ void __launch_bounds__(1024) k_zero(u32* __restrict__ cellCount) {
    if (threadIdx.x < NCELL) cellCount[threadIdx.x] = 0;
}

// ---------------------------------------------------------------------------
// Histogram anchors per cell (LDS-aggregated).
__global__ void __launch_bounds__(256) k_hist(
    const float4* __restrict__ anchor, u32* __restrict__ cellCount, int N)
{
    __shared__ u32 h[NCELL];
    const int tid = threadIdx.x;
    for (int c = tid; c < NCELL; c += 256) h[c] = 0;
    __syncthreads();
    for (int i = blockIdx.x * 256 + tid; i < N; i += 256 * gridDim.x)
        atomicAdd(&h[cell_of(anchor[i])], 1u);
    __syncthreads();
    for (int c = tid; c < NCELL; c += 256)
        if (h[c]) atomicAdd(&cellCount[c], h[c]);
}

// ---------------------------------------------------------------------------
// Exclusive scan + cursor init + per-cell GT lists (LDS-atomic slots).
__global__ void __launch_bounds__(256) k_scan(
    const u32* __restrict__ cellCount, u32* __restrict__ cellStart,
    u32* __restrict__ cellCursor, const float4* __restrict__ gt,
    u32* __restrict__ gtCnt, u16* __restrict__ gtIds, int M)
{
    __shared__ u32 l_cnt[NCELL];
    const int tid = threadIdx.x;
    for (int c = tid; c < NCELL; c += 256) l_cnt[c] = 0;
    if (tid == 0) {
        u32 s = 0;
        for (int c = 0; c < NCELL; ++c) { cellStart[c] = s; s += cellCount[c]; }
        cellStart[NCELL] = s;
    }
    __syncthreads();
    for (int c = tid; c < NCELL; c += 256) cellCursor[c] = cellStart[c];
    if (tid < M) {
        float4 g = gt[tid];
        int clx, chx, cly, chy;
        gt_range(g, clx, chx, cly, chy);
        for (int iy = cly; iy <= chy; ++iy)
            for (int ix = clx; ix <= chx; ++ix) {
                int c = iy * NCX + ix;
                u32 slot = atomicAdd(&l_cnt[c], 1u);
                gtIds[(size_t)c * M + slot] = (u16)tid;
            }
    }
    __syncthreads();
    for (int c = tid; c < NCELL; c += 256) gtCnt[c] = l_cnt[c];
}

// ---------------------------------------------------------------------------
// Scatter anchors into cell-binned order.
__global__ void __launch_bounds__(256) k_scatter(
    const float4* __restrict__ anchor, u32* __restrict__ cellCursor,
    float4* __restrict__ binnedBox, int* __restrict__ binnedIdx, int N)
{
    int i = blockIdx.x * 256 + threadIdx.x;
    if (i >= N) return;
    float4 a = anchor[i];
    u32 pos = atomicAdd(&cellCursor[cell_of(a)], 1u);
    binnedBox[pos] = a;
    binnedIdx[pos] = i;
}

// ---------------------------------------------------------------------------
// Base assignment: each binned anchor vs its cell's GT list.
__global__ void __launch_bounds__(256) k_assign(
    const float4* __restrict__ binnedBox, const int* __restrict__ binnedIdx,
    const float4* __restrict__ gt, const u32* __restrict__ gtCnt,
    const u16* __restrict__ gtIds, int* __restrict__ out, int N, int M)
{
    __shared__ float4 s_g[MPAD];
    __shared__ float  s_ga[MPAD];
    const int tid = threadIdx.x;
    if (tid < M) {
        float4 g = gt[tid];
        s_g[tid]  = g;
        s_ga[tid] = (g.z - g.x) * (g.w - g.y);
    }
    __syncthreads();

    int p = blockIdx.x * 256 + tid;
    if (p >= N) return;
    float4 a  = binnedBox[p];
    int   idx = binnedIdx[p];
    float area_a = (a.z - a.x) * (a.w - a.y);
    int c   = cell_of(a);
    int cnt = (int)gtCnt[c];
    const u16* list = gtIds + (size_t)c * M;

    u64 best = 0;
    for (int k = 0; k < cnt; ++k) {
        int m = list[k];
        float4 g = s_g[m];
        float inter, iou;
        IOU_EVAL(a, area_a, g, s_ga[m], inter, iou);
        if (inter > 0.0f) {
            u64 key = ((u64)__float_as_uint(iou) << 32) | (~(u32)m);
            best = key > best ? key : best;
        }
    }
    u32 ib = (u32)(best >> 32);
    int v = -2;
    if (ib < __float_as_uint(NEG_THRESH)) v = -1;   // max iou < 0.3 (incl 0)
    if (ib > __float_as_uint(POS_THRESH)) v = (int)(~(u32)best);
    out[idx] = v;
}

// ---------------------------------------------------------------------------
// Per-GT top-3 over its covered cells' binned anchors. grid = M blocks x 512.
// Seeds (0,~0),(0,~1),(0,~2) reproduce the reference zero-iou index fill;
// duplicates of seed keys across lanes are harmless (only surface when the
// corresponding claim is dead via the > 0.1 gate, or for k==0 where a0 = 0
// matches ranks[m,0] = 0 in the all-zero case).
__global__ void __launch_bounds__(512) k_top3(
    const float4* __restrict__ binnedBox, const int* __restrict__ binnedIdx,
    const float4* __restrict__ gt, const u32* __restrict__ cellStart,
    u64* __restrict__ final3, int M)
{
    const int m    = blockIdx.x;
    const int tid  = threadIdx.x;
    const int lane = tid & 63;
    const int w    = tid >> 6;

    float4 g = gt[m];
    float area_g = (g.z - g.x) * (g.w - g.y);
    int clx, chx, cly, chy;
    gt_range(g, clx, chx, cly, chy);

    u64 t0 = 0x00000000FFFFFFFFULL;   // (iou=0, ~0)
    u64 t1 = 0x00000000FFFFFFFEULL;   // (iou=0, ~1)
    u64 t2 = 0x00000000FFFFFFFDULL;   // (iou=0, ~2)

    for (int iy = cly; iy <= chy; ++iy)
        for (int ix = clx; ix <= chx; ++ix) {
            int c = iy * NCX + ix;
            int s = (int)cellStart[c];
            int e = (int)cellStart[c + 1];
            for (int p = s + tid; p < e; p += 512) {
                float4 a = binnedBox[p];
                int  idx = binnedIdx[p];
                float area_a = (a.z - a.x) * (a.w - a.y);
                float inter, iou;
                IOU_EVAL(a, area_a, g, area_g, inter, iou);
                if (inter > 0.0f) {
                    u64 key = ((u64)__float_as_uint(iou) << 32) | (~(u32)idx);
                    INS3(t0, t1, t2, key);
                }
            }
        }

    for (int off = 1; off < 64; off <<= 1) {
        u64 o0 = shfl_xor_u64(t0, off);
        u64 o1 = shfl_xor_u64(t1, off);
        u64 o2 = shfl_xor_u64(t2, off);
        INS3(t0, t1, t2, o0);
        INS3(t0, t1, t2, o1);
        INS3(t0, t1, t2, o2);
    }

    __shared__ u64 s_red[8][3];
    if (lane == 0) { s_red[w][0] = t0; s_red[w][1] = t1; s_red[w][2] = t2; }
    __syncthreads();
    if (tid == 0) {
        u64 q0 = 0, q1 = 0, q2 = 0;
        for (int wv = 0; wv < 8; ++wv) {
            INS3(q0, q1, q2, s_red[wv][0]);
            INS3(q0, q1, q2, s_red[wv][1]);
            INS3(q0, q1, q2, s_red[wv][2]);
        }
        final3[m * 3 + 0] = q0;
        final3[m * 3 + 1] = q1;
        final3[m * 3 + 2] = q2;
    }
}

// ---------------------------------------------------------------------------
// Claims: forced-claim scatter-max, break-free. key = (anchor<<32)|(gt+1).
__global__ void __launch_bounds__(256) k_claims(
    const u64* __restrict__ final3, int* __restrict__ out, int M)
{
    __shared__ u64 s_key[3 * MPAD];
    const int tid = threadIdx.x;

    if (tid < M) {
        u64 q0 = final3[tid * 3 + 0];
        u64 q1 = final3[tid * 3 + 1];
        u64 q2 = final3[tid * 3 + 2];
        float v0 = __uint_as_float((u32)(q0 >> 32));
        float v1 = __uint_as_float((u32)(q1 >> 32));
        float v2 = __uint_as_float((u32)(q2 >> 32));
        u32 a0 = ~(u32)q0;
        u32 a1 = ~(u32)q1;
        u32 a2 = ~(u32)q2;

        int npos = (v0 > POS_THRESH) + (v1 > POS_THRESH) + (v2 > POS_THRESH);
        bool low = npos < 3;

        s_key[tid * 3 + 0] = ((u64)a0 << 32) | (u32)(tid + 1);   // k==0 forced
        s_key[tid * 3 + 1] = (low && v1 > CLAIM_THRESH)
            ? (((u64)a1 << 32) | (u32)(tid + 1)) : 0ULL;
        s_key[tid * 3 + 2] = (low && v2 > CLAIM_THRESH)
            ? (((u64)a2 << 32) | (u32)(tid + 1)) : 0ULL;
    }
    __syncthreads();

    const int tote = 3 * M;
    for (int e = tid; e < tote; e += 256) {
        u64 my = s_key[e];
        if (my == 0) continue;
        u32 myA = (u32)(my >> 32);
        u64 mx = 0;
        for (int f = 0; f < tote; ++f) {          // break-free: pipelineable
            u64 k = s_key[f];
            bool same = (u32)(k >> 32) == myA;
            if (same && k > mx) mx = k;
        }
        if (mx == my) out[myA] = (int)(my & 0xffffffffULL) - 1;
    }
}

// ---------------------------------------------------------------------------
extern "C" void kernel_launch(void* const* d_in, const int* in_sizes, int n_in,
                              void* d_out, int out_size, void* d_ws, size_t ws_size,
                              hipStream_t stream) {
    const float4* anchor = (const float4*)d_in[0];
    const float4* gt     = (const float4*)d_in[1];
    int N = in_sizes[0] / 4;
    int M = in_sizes[1] / 4;
    int* out = (int*)d_out;

    // workspace layout (~10.43 MB for N=500k, M=200; proven ws >= 10.61 MB)
    char* ws = (char*)d_ws;
    size_t off = 0;
    auto alloc = [&](size_t bytes, size_t align) -> void* {
        off = (off + align - 1) / align * align;
        void* p = ws + off;
        off += bytes;
        return p;
    };
    u32* cellCount  = (u32*)alloc(NCELL * 4, 4);
    u32* cellStart  = (u32*)alloc((NCELL + 1) * 4, 4);
    u32* cellCursor = (u32*)alloc(NCELL * 4, 4);
    u32* gtCnt      = (u32*)alloc(NCELL * 4, 4);
    u64* final3     = (u64*)alloc(3 * MPAD * 8, 8);
    u16* gtIds      = (u16*)alloc((size_t)NCELL * M * 2, 2);
    float4* binnedBox = (float4*)alloc((size_t)N * 16, 16);
    int* binnedIdx    = (int*)alloc((size_t)N * 4, 4);

    int nb = (N + 255) / 256;
    k_zero<<<1, 1024, 0, stream>>>(cellCount);
    k_hist<<<256, 256, 0, stream>>>(anchor, cellCount, N);
    k_scan<<<1, 256, 0, stream>>>(cellCount, cellStart, cellCursor,
                                  gt, gtCnt, gtIds, M);
    k_scatter<<<nb, 256, 0, stream>>>(anchor, cellCursor, binnedBox,
                                      binnedIdx, N);
    k_assign<<<nb, 256, 0, stream>>>(binnedBox, binnedIdx, gt, gtCnt, gtIds,
                                     out, N, M);
    k_top3<<<M, 512, 0, stream>>>(binnedBox, binnedIdx, gt, cellStart,
                                  final3, M);
    k_claims<<<1, 256, 0, stream>>>(final3, out, M);
}

// Round 9
// 234.593 us; speedup vs baseline: 1.3740x; 1.3740x over previous
//
#include <hip/hip_runtime.h>
#include <stdint.h>

// S3FD anchor assignment — spatially-binned exact rewrite, round 9.
// d_in[0]: anchor [N,4] f32, d_in[1]: gt [M,4] f32. d_out: assign [N] int32.
//
// Round 8 post-mortem: k_top3 ran 119 us at 8% occupancy (grid = 200 blocks)
// and k_scan hid a serial 1024-iter dependent-load scan on thread 0.
// Round 9: k_top3 striped S=10 ways per GT (2000 blocks, stripe partials
// merged in k_claims); k_scan uses a 256-thread Hillis-Steele LDS scan;
// k_zero replaced by hipMemsetAsync. hist/scatter/assign/claims unchanged.
//
// Key encoding (exact jax semantics), per-GT top-3:
//   key = (iou_bits << 32) | ~anchor_idx    (stable top_k: higher iou, then
//                                            lower anchor index wins)
// Zero-iou seed keys (0,~0),(0,~1),(0,~2) reproduce the reference's
// index-ordered zero fill; duplicated seeds across stripes are benign (they
// can only occupy slots whose claims die on the > 0.1 gate; the all-zero
// case yields anchor 0 == reference ranks[m,0]).

typedef unsigned int u32;
typedef unsigned short u16;
typedef unsigned long long u64;

#define POS_THRESH 0.5f
#define NEG_THRESH 0.3f
#define CLAIM_THRESH 0.1f

constexpr int NCX = 32, NCY = 32, NCELL = NCX * NCY;  // 32x32 cells, 32 px
constexpr float INV_CELL = 0.03125f;                  // 1/32
constexpr float MARGIN = 64.5f;   // max anchor half-extent (<64.001) + slack
constexpr int MPAD = 256;         // padded GT count (M = 200)
constexpr int NSTRIPE = 10;       // k_top3 stripes per GT

#define INS3(t0, t1, t2, k) do {                                  \
    if ((k) > (t2)) {                                             \
        if ((k) > (t0))      { t2 = t1; t1 = t0; t0 = (k); }      \
        else if ((k) > (t1)) { t2 = t1; t1 = (k); }               \
        else                 { t2 = (k); }                        \
    } } while (0)

// IoU expression verbatim from the passing rounds (numpy-exact).
#define IOU_EVAL(a, areaA, g, areaG, inter, iou) {                \
    float ltx = fmaxf(a.x, g.x), lty = fmaxf(a.y, g.y);           \
    float rbx = fminf(a.z, g.z), rby = fminf(a.w, g.w);           \
    float ww = fmaxf(rbx - ltx, 0.0f);                            \
    float hh = fmaxf(rby - lty, 0.0f);                            \
    inter = ww * hh;                                              \
    iou = 0.0f;                                                   \
    if (inter > 0.0f) iou = inter / ((areaA + areaG) - inter);    \
}

__device__ __forceinline__ u64 shfl_xor_u64(u64 x, int mask) {
    int lo = __shfl_xor((int)(u32)x, mask, 64);
    int hi = __shfl_xor((int)(u32)(x >> 32), mask, 64);
    return ((u64)(u32)hi << 32) | (u32)lo;
}

__device__ __forceinline__ int cell_of(const float4 a) {
    float cx = 0.5f * (a.x + a.z);
    float cy = 0.5f * (a.y + a.w);
    int ix = (int)(cx * INV_CELL);
    int iy = (int)(cy * INV_CELL);
    ix = ix < 0 ? 0 : (ix > NCX - 1 ? NCX - 1 : ix);
    iy = iy < 0 ? 0 : (iy > NCY - 1 ? NCY - 1 : iy);
    return iy * NCX + ix;
}

__device__ __forceinline__ void gt_range(const float4 g, int& clx, int& chx,
                                         int& cly, int& chy) {
    clx = (int)floorf((g.x - MARGIN) * INV_CELL);
    chx = (int)floorf((g.z + MARGIN) * INV_CELL);
    cly = (int)floorf((g.y - MARGIN) * INV_CELL);
    chy = (int)floorf((g.w + MARGIN) * INV_CELL);
    clx = clx < 0 ? 0 : (clx > NCX - 1 ? NCX - 1 : clx);
    chx = chx < 0 ? 0 : (chx > NCX - 1 ? NCX - 1 : chx);
    cly = cly < 0 ? 0 : (cly > NCY - 1 ? NCY - 1 : cly);
    chy = chy < 0 ? 0 : (chy > NCY - 1 ? NCY - 1 : chy);
}

// ---------------------------------------------------------------------------
// Histogram anchors per cell (LDS-aggregated).
__global__ void __launch_bounds__(256) k_hist(
    const float4* __restrict__ anchor, u32* __restrict__ cellCount, int N)
{
    __shared__ u32 h[NCELL];
    const int tid = threadIdx.x;
    for (int c = tid; c < NCELL; c += 256) h[c] = 0;
    __syncthreads();
    for (int i = blockIdx.x * 256 + tid; i < N; i += 256 * gridDim.x)
        atomicAdd(&h[cell_of(anchor[i])], 1u);
    __syncthreads();
    for (int c = tid; c < NCELL; c += 256)
        if (h[c]) atomicAdd(&cellCount[c], h[c]);
}

// ---------------------------------------------------------------------------
// Parallel exclusive scan (Hillis-Steele, 4 cells/thread) + cursor init +
// per-cell GT lists (LDS-atomic slots; list order nondeterministic but all
// consumers are order-independent key-maxes).
__global__ void __launch_bounds__(256) k_scan(
    const u32* __restrict__ cellCount, u32* __restrict__ cellStart,
    u32* __restrict__ cellCursor, const float4* __restrict__ gt,
    u32* __restrict__ gtCnt, u16* __restrict__ gtIds, int M)
{
    __shared__ u32 s_sum[256];
    __shared__ u32 l_cnt[NCELL];
    const int tid = threadIdx.x;

    u32 c0 = cellCount[tid * 4 + 0];
    u32 c1 = cellCount[tid * 4 + 1];
    u32 c2 = cellCount[tid * 4 + 2];
    u32 c3 = cellCount[tid * 4 + 3];
    s_sum[tid] = c0 + c1 + c2 + c3;
    for (int c = tid; c < NCELL; c += 256) l_cnt[c] = 0;
    __syncthreads();

    for (int off = 1; off < 256; off <<= 1) {
        u32 v = (tid >= off) ? s_sum[tid - off] : 0;
        __syncthreads();
        s_sum[tid] += v;
        __syncthreads();
    }

    u32 base = tid ? s_sum[tid - 1] : 0;
    cellStart[tid * 4 + 0] = base;          cellCursor[tid * 4 + 0] = base;
    base += c0;
    cellStart[tid * 4 + 1] = base;          cellCursor[tid * 4 + 1] = base;
    base += c1;
    cellStart[tid * 4 + 2] = base;          cellCursor[tid * 4 + 2] = base;
    base += c2;
    cellStart[tid * 4 + 3] = base;          cellCursor[tid * 4 + 3] = base;
    if (tid == 255) cellStart[NCELL] = s_sum[255];

    if (tid < M) {
        float4 g = gt[tid];
        int clx, chx, cly, chy;
        gt_range(g, clx, chx, cly, chy);
        for (int iy = cly; iy <= chy; ++iy)
            for (int ix = clx; ix <= chx; ++ix) {
                int c = iy * NCX + ix;
                u32 slot = atomicAdd(&l_cnt[c], 1u);
                gtIds[(size_t)c * M + slot] = (u16)tid;
            }
    }
    __syncthreads();
    for (int c = tid; c < NCELL; c += 256) gtCnt[c] = l_cnt[c];
}

// ---------------------------------------------------------------------------
// Scatter anchors into cell-binned order.
__global__ void __launch_bounds__(256) k_scatter(
    const float4* __restrict__ anchor, u32* __restrict__ cellCursor,
    float4* __restrict__ binnedBox, int* __restrict__ binnedIdx, int N)
{
    int i = blockIdx.x * 256 + threadIdx.x;
    if (i >= N) return;
    float4 a = anchor[i];
    u32 pos = atomicAdd(&cellCursor[cell_of(a)], 1u);
    binnedBox[pos] = a;
    binnedIdx[pos] = i;
}

// ---------------------------------------------------------------------------
// Base assignment: each binned anchor vs its cell's GT list (uniform cnt
// within a block since binned order groups same-cell anchors).
__global__ void __launch_bounds__(256) k_assign(
    const float4* __restrict__ binnedBox, const int* __restrict__ binnedIdx,
    const float4* __restrict__ gt, const u32* __restrict__ gtCnt,
    const u16* __restrict__ gtIds, int* __restrict__ out, int N, int M)
{
    __shared__ float4 s_g[MPAD];
    __shared__ float  s_ga[MPAD];
    const int tid = threadIdx.x;
    if (tid < M) {
        float4 g = gt[tid];
        s_g[tid]  = g;
        s_ga[tid] = (g.z - g.x) * (g.w - g.y);
    }
    __syncthreads();

    int p = blockIdx.x * 256 + tid;
    if (p >= N) return;
    float4 a  = binnedBox[p];
    int   idx = binnedIdx[p];
    float area_a = (a.z - a.x) * (a.w - a.y);
    int c   = cell_of(a);
    int cnt = (int)gtCnt[c];
    const u16* list = gtIds + (size_t)c * M;

    u64 best = 0;
    for (int k = 0; k < cnt; ++k) {
        int m = list[k];
        float4 g = s_g[m];
        float inter, iou;
        IOU_EVAL(a, area_a, g, s_ga[m], inter, iou);
        if (inter > 0.0f) {
            u64 key = ((u64)__float_as_uint(iou) << 32) | (~(u32)m);
            best = key > best ? key : best;
        }
    }
    u32 ib = (u32)(best >> 32);
    int v = -2;
    if (ib < __float_as_uint(NEG_THRESH)) v = -1;   // max iou < 0.3 (incl 0)
    if (ib > __float_as_uint(POS_THRESH)) v = (int)(~(u32)best);
    out[idx] = v;
}

// ---------------------------------------------------------------------------
// Per-GT top-3, striped: grid (NSTRIPE, M) x 256. Block (s,m) takes every
// NSTRIPE-th covered cell of GT m; writes stripe partial (3 u64).
__global__ void __launch_bounds__(256) k_top3(
    const float4* __restrict__ binnedBox, const int* __restrict__ binnedIdx,
    const float4* __restrict__ gt, const u32* __restrict__ cellStart,
    u64* __restrict__ partial3, int M)
{
    const int s    = blockIdx.x;
    const int m    = blockIdx.y;
    const int tid  = threadIdx.x;
    const int lane = tid & 63;
    const int w    = tid >> 6;

    float4 g = gt[m];
    float area_g = (g.z - g.x) * (g.w - g.y);
    int clx, chx, cly, chy;
    gt_range(g, clx, chx, cly, chy);

    u64 t0 = 0x00000000FFFFFFFFULL;   // (iou=0, ~0)
    u64 t1 = 0x00000000FFFFFFFEULL;   // (iou=0, ~1)
    u64 t2 = 0x00000000FFFFFFFDULL;   // (iou=0, ~2)

    int q = 0;
    for (int iy = cly; iy <= chy; ++iy)
        for (int ix = clx; ix <= chx; ++ix, ++q) {
            if (q % NSTRIPE != s) continue;
            int c = iy * NCX + ix;
            int cs = (int)cellStart[c];
            int ce = (int)cellStart[c + 1];
            for (int p = cs + tid; p < ce; p += 256) {
                float4 a = binnedBox[p];
                int  idx = binnedIdx[p];
                float area_a = (a.z - a.x) * (a.w - a.y);
                float inter, iou;
                IOU_EVAL(a, area_a, g, area_g, inter, iou);
                if (inter > 0.0f) {
                    u64 key = ((u64)__float_as_uint(iou) << 32) | (~(u32)idx);
                    INS3(t0, t1, t2, key);
                }
            }
        }

    for (int off = 1; off < 64; off <<= 1) {
        u64 o0 = shfl_xor_u64(t0, off);
        u64 o1 = shfl_xor_u64(t1, off);
        u64 o2 = shfl_xor_u64(t2, off);
        INS3(t0, t1, t2, o0);
        INS3(t0, t1, t2, o1);
        INS3(t0, t1, t2, o2);
    }

    __shared__ u64 s_red[4][3];
    if (lane == 0) { s_red[w][0] = t0; s_red[w][1] = t1; s_red[w][2] = t2; }
    __syncthreads();
    if (tid == 0) {
        u64 q0 = 0, q1 = 0, q2 = 0;
        for (int wv = 0; wv < 4; ++wv) {
            INS3(q0, q1, q2, s_red[wv][0]);
            INS3(q0, q1, q2, s_red[wv][1]);
            INS3(q0, q1, q2, s_red[wv][2]);
        }
        size_t b = ((size_t)m * NSTRIPE + s) * 3;
        partial3[b + 0] = q0;
        partial3[b + 1] = q1;
        partial3[b + 2] = q2;
    }
}

// ---------------------------------------------------------------------------
// Claims: merge stripe partials, then forced-claim scatter-max (break-free).
// claim key = (anchor<<32)|(gt+1); winner = max key among same-anchor claims.
__global__ void __launch_bounds__(256) k_claims(
    const u64* __restrict__ partial3, int* __restrict__ out, int M)
{
    __shared__ u64 s_key[3 * MPAD];
    const int tid = threadIdx.x;

    if (tid < M) {
        u64 q0 = 0, q1 = 0, q2 = 0;
        const u64* p = partial3 + (size_t)tid * NSTRIPE * 3;
        for (int c = 0; c < NSTRIPE * 3; ++c) INS3(q0, q1, q2, p[c]);

        float v0 = __uint_as_float((u32)(q0 >> 32));
        float v1 = __uint_as_float((u32)(q1 >> 32));
        float v2 = __uint_as_float((u32)(q2 >> 32));
        u32 a0 = ~(u32)q0;
        u32 a1 = ~(u32)q1;
        u32 a2 = ~(u32)q2;

        int npos = (v0 > POS_THRESH) + (v1 > POS_THRESH) + (v2 > POS_THRESH);
        bool low = npos < 3;

        s_key[tid * 3 + 0] = ((u64)a0 << 32) | (u32)(tid + 1);   // k==0 forced
        s_key[tid * 3 + 1] = (low && v1 > CLAIM_THRESH)
            ? (((u64)a1 << 32) | (u32)(tid + 1)) : 0ULL;
        s_key[tid * 3 + 2] = (low && v2 > CLAIM_THRESH)
            ? (((u64)a2 << 32) | (u32)(tid + 1)) : 0ULL;
    }
    __syncthreads();

    const int tote = 3 * M;
    for (int e = tid; e < tote; e += 256) {
        u64 my = s_key[e];
        if (my == 0) continue;
        u32 myA = (u32)(my >> 32);
        u64 mx = 0;
        for (int f = 0; f < tote; ++f) {          // break-free: pipelineable
            u64 k = s_key[f];
            bool same = (u32)(k >> 32) == myA;
            if (same && k > mx) mx = k;
        }
        if (mx == my) out[myA] = (int)(my & 0xffffffffULL) - 1;
    }
}

// ---------------------------------------------------------------------------
extern "C" void kernel_launch(void* const* d_in, const int* in_sizes, int n_in,
                              void* d_out, int out_size, void* d_ws, size_t ws_size,
                              hipStream_t stream) {
    const float4* anchor = (const float4*)d_in[0];
    const float4* gt     = (const float4*)d_in[1];
    int N = in_sizes[0] / 4;
    int M = in_sizes[1] / 4;
    int* out = (int*)d_out;

    // workspace layout (~10.48 MB for N=500k, M=200; <= proven 10.61 MB)
    char* ws = (char*)d_ws;
    size_t off = 0;
    auto alloc = [&](size_t bytes, size_t align) -> void* {
        off = (off + align - 1) / align * align;
        void* p = ws + off;
        off += bytes;
        return p;
    };
    u32* cellCount  = (u32*)alloc(NCELL * 4, 4);
    u32* cellStart  = (u32*)alloc((NCELL + 1) * 4, 4);
    u32* cellCursor = (u32*)alloc(NCELL * 4, 4);
    u32* gtCnt      = (u32*)alloc(NCELL * 4, 4);
    u64* partial3   = (u64*)alloc((size_t)MPAD * NSTRIPE * 3 * 8, 8);
    u16* gtIds      = (u16*)alloc((size_t)NCELL * M * 2, 2);
    float4* binnedBox = (float4*)alloc((size_t)N * 16, 16);
    int* binnedIdx    = (int*)alloc((size_t)N * 4, 4);

    int nb = (N + 255) / 256;
    hipMemsetAsync(cellCount, 0, NCELL * sizeof(u32), stream);
    k_hist<<<256, 256, 0, stream>>>(anchor, cellCount, N);
    k_scan<<<1, 256, 0, stream>>>(cellCount, cellStart, cellCursor,
                                  gt, gtCnt, gtIds, M);
    k_scatter<<<nb, 256, 0, stream>>>(anchor, cellCursor, binnedBox,
                                      binnedIdx, N);
    k_assign<<<nb, 256, 0, stream>>>(binnedBox, binnedIdx, gt, gtCnt, gtIds,
                                     out, N, M);
    k_top3<<<dim3(NSTRIPE, M), 256, 0, stream>>>(binnedBox, binnedIdx, gt,
                                                 cellStart, partial3, M);
    k_claims<<<1, 256, 0, stream>>>(partial3, out, M);
}

// Round 10
// 161.678 us; speedup vs baseline: 1.9936x; 1.4510x over previous
//
#include <hip/hip_runtime.h>
#include <stdint.h>

// S3FD anchor assignment — spatially-binned exact rewrite, round 10.
// d_in[0]: anchor [N,4] f32, d_in[1]: gt [M,4] f32. d_out: assign [N] int32.
//
// Round 9 post-mortem: k_scatter 104 us at VALUBusy 0.2%, 436 GB/s — atomic
// serialization on 1024 dense u32 cursors (= 64 cachelines, 16 counters per
// line false-shared). Round 10: counters padded to ONE PER 64B LINE (stride
// 16 u32); one padded array serves as hist target then is rewritten in-place
// as the scatter cursor. k_hist drops to 128 grid-stride blocks. All consumer
// kernels unchanged from the passing round-9 code.
//
// Key encoding (exact jax semantics), per-GT top-3:
//   key = (iou_bits << 32) | ~anchor_idx    (stable top_k: higher iou, then
//                                            lower anchor index wins)
// Zero-iou seed keys (0,~0),(0,~1),(0,~2) reproduce the reference's
// index-ordered zero fill; duplicated seeds across stripes are benign.

typedef unsigned int u32;
typedef unsigned short u16;
typedef unsigned long long u64;

#define POS_THRESH 0.5f
#define NEG_THRESH 0.3f
#define CLAIM_THRESH 0.1f

constexpr int NCX = 32, NCY = 32, NCELL = NCX * NCY;  // 32x32 cells, 32 px
constexpr float INV_CELL = 0.03125f;                  // 1/32
constexpr float MARGIN = 64.5f;   // max anchor half-extent (<64.001) + slack
constexpr int MPAD = 256;         // padded GT count (M = 200)
constexpr int NSTRIPE = 10;       // k_top3 stripes per GT
constexpr int CPAD = 16;          // u32 stride per counter = one 64B line

#define INS3(t0, t1, t2, k) do {                                  \
    if ((k) > (t2)) {                                             \
        if ((k) > (t0))      { t2 = t1; t1 = t0; t0 = (k); }      \
        else if ((k) > (t1)) { t2 = t1; t1 = (k); }               \
        else                 { t2 = (k); }                        \
    } } while (0)

// IoU expression verbatim from the passing rounds (numpy-exact).
#define IOU_EVAL(a, areaA, g, areaG, inter, iou) {                \
    float ltx = fmaxf(a.x, g.x), lty = fmaxf(a.y, g.y);           \
    float rbx = fminf(a.z, g.z), rby = fminf(a.w, g.w);           \
    float ww = fmaxf(rbx - ltx, 0.0f);                            \
    float hh = fmaxf(rby - lty, 0.0f);                            \
    inter = ww * hh;                                              \
    iou = 0.0f;                                                   \
    if (inter > 0.0f) iou = inter / ((areaA + areaG) - inter);    \
}

__device__ __forceinline__ u64 shfl_xor_u64(u64 x, int mask) {
    int lo = __shfl_xor((int)(u32)x, mask, 64);
    int hi = __shfl_xor((int)(u32)(x >> 32), mask, 64);
    return ((u64)(u32)hi << 32) | (u32)lo;
}

__device__ __forceinline__ int cell_of(const float4 a) {
    float cx = 0.5f * (a.x + a.z);
    float cy = 0.5f * (a.y + a.w);
    int ix = (int)(cx * INV_CELL);
    int iy = (int)(cy * INV_CELL);
    ix = ix < 0 ? 0 : (ix > NCX - 1 ? NCX - 1 : ix);
    iy = iy < 0 ? 0 : (iy > NCY - 1 ? NCY - 1 : iy);
    return iy * NCX + ix;
}

__device__ __forceinline__ void gt_range(const float4 g, int& clx, int& chx,
                                         int& cly, int& chy) {
    clx = (int)floorf((g.x - MARGIN) * INV_CELL);
    chx = (int)floorf((g.z + MARGIN) * INV_CELL);
    cly = (int)floorf((g.y - MARGIN) * INV_CELL);
    chy = (int)floorf((g.w + MARGIN) * INV_CELL);
    clx = clx < 0 ? 0 : (clx > NCX - 1 ? NCX - 1 : clx);
    chx = chx < 0 ? 0 : (chx > NCX - 1 ? NCX - 1 : chx);
    cly = cly < 0 ? 0 : (cly > NCY - 1 ? NCY - 1 : cly);
    chy = chy < 0 ? 0 : (chy > NCY - 1 ? NCY - 1 : chy);
}

// ---------------------------------------------------------------------------
// Histogram anchors per cell (LDS-aggregated; padded global counters).
__global__ void __launch_bounds__(256) k_hist(
    const float4* __restrict__ anchor, u32* __restrict__ ccPad, int N)
{
    __shared__ u32 h[NCELL];
    const int tid = threadIdx.x;
    for (int c = tid; c < NCELL; c += 256) h[c] = 0;
    __syncthreads();
    for (int i = blockIdx.x * 256 + tid; i < N; i += 256 * gridDim.x)
        atomicAdd(&h[cell_of(anchor[i])], 1u);
    __syncthreads();
    for (int c = tid; c < NCELL; c += 256)
        if (h[c]) atomicAdd(&ccPad[c * CPAD], h[c]);
}

// ---------------------------------------------------------------------------
// Parallel exclusive scan (Hillis-Steele, 4 cells/thread); writes dense
// cellStart and rewrites ccPad in-place count -> cursor. Also builds per-cell
// GT lists (LDS-atomic slots; order nondeterministic, consumers are
// order-independent key-maxes).
__global__ void __launch_bounds__(256) k_scan(
    u32* __restrict__ ccPad, u32* __restrict__ cellStart,
    const float4* __restrict__ gt,
    u32* __restrict__ gtCnt, u16* __restrict__ gtIds, int M)
{
    __shared__ u32 s_sum[256];
    __shared__ u32 l_cnt[NCELL];
    const int tid = threadIdx.x;

    u32 c0 = ccPad[(tid * 4 + 0) * CPAD];
    u32 c1 = ccPad[(tid * 4 + 1) * CPAD];
    u32 c2 = ccPad[(tid * 4 + 2) * CPAD];
    u32 c3 = ccPad[(tid * 4 + 3) * CPAD];
    s_sum[tid] = c0 + c1 + c2 + c3;
    for (int c = tid; c < NCELL; c += 256) l_cnt[c] = 0;
    __syncthreads();

    for (int off = 1; off < 256; off <<= 1) {
        u32 v = (tid >= off) ? s_sum[tid - off] : 0;
        __syncthreads();
        s_sum[tid] += v;
        __syncthreads();
    }

    u32 base = tid ? s_sum[tid - 1] : 0;
    cellStart[tid * 4 + 0] = base;  ccPad[(tid * 4 + 0) * CPAD] = base;
    base += c0;
    cellStart[tid * 4 + 1] = base;  ccPad[(tid * 4 + 1) * CPAD] = base;
    base += c1;
    cellStart[tid * 4 + 2] = base;  ccPad[(tid * 4 + 2) * CPAD] = base;
    base += c2;
    cellStart[tid * 4 + 3] = base;  ccPad[(tid * 4 + 3) * CPAD] = base;
    if (tid == 255) cellStart[NCELL] = s_sum[255];

    if (tid < M) {
        float4 g = gt[tid];
        int clx, chx, cly, chy;
        gt_range(g, clx, chx, cly, chy);
        for (int iy = cly; iy <= chy; ++iy)
            for (int ix = clx; ix <= chx; ++ix) {
                int c = iy * NCX + ix;
                u32 slot = atomicAdd(&l_cnt[c], 1u);
                gtIds[(size_t)c * M + slot] = (u16)tid;
            }
    }
    __syncthreads();
    for (int c = tid; c < NCELL; c += 256) gtCnt[c] = l_cnt[c];
}

// ---------------------------------------------------------------------------
// Scatter anchors into cell-binned order (padded cursors: 1 line per cell).
__global__ void __launch_bounds__(256) k_scatter(
    const float4* __restrict__ anchor, u32* __restrict__ ccPad,
    float4* __restrict__ binnedBox, int* __restrict__ binnedIdx, int N)
{
    int i = blockIdx.x * 256 + threadIdx.x;
    if (i >= N) return;
    float4 a = anchor[i];
    u32 pos = atomicAdd(&ccPad[cell_of(a) * CPAD], 1u);
    binnedBox[pos] = a;
    binnedIdx[pos] = i;
}

// ---------------------------------------------------------------------------
// Base assignment: each binned anchor vs its cell's GT list (uniform cnt
// within a block since binned order groups same-cell anchors).
__global__ void __launch_bounds__(256) k_assign(
    const float4* __restrict__ binnedBox, const int* __restrict__ binnedIdx,
    const float4* __restrict__ gt, const u32* __restrict__ gtCnt,
    const u16* __restrict__ gtIds, int* __restrict__ out, int N, int M)
{
    __shared__ float4 s_g[MPAD];
    __shared__ float  s_ga[MPAD];
    const int tid = threadIdx.x;
    if (tid < M) {
        float4 g = gt[tid];
        s_g[tid]  = g;
        s_ga[tid] = (g.z - g.x) * (g.w - g.y);
    }
    __syncthreads();

    int p = blockIdx.x * 256 + tid;
    if (p >= N) return;
    float4 a  = binnedBox[p];
    int   idx = binnedIdx[p];
    float area_a = (a.z - a.x) * (a.w - a.y);
    int c   = cell_of(a);
    int cnt = (int)gtCnt[c];
    const u16* list = gtIds + (size_t)c * M;

    u64 best = 0;
    for (int k = 0; k < cnt; ++k) {
        int m = list[k];
        float4 g = s_g[m];
        float inter, iou;
        IOU_EVAL(a, area_a, g, s_ga[m], inter, iou);
        if (inter > 0.0f) {
            u64 key = ((u64)__float_as_uint(iou) << 32) | (~(u32)m);
            best = key > best ? key : best;
        }
    }
    u32 ib = (u32)(best >> 32);
    int v = -2;
    if (ib < __float_as_uint(NEG_THRESH)) v = -1;   // max iou < 0.3 (incl 0)
    if (ib > __float_as_uint(POS_THRESH)) v = (int)(~(u32)best);
    out[idx] = v;
}

// ---------------------------------------------------------------------------
// Per-GT top-3, striped: grid (NSTRIPE, M) x 256. Block (s,m) takes every
// NSTRIPE-th covered cell of GT m; writes stripe partial (3 u64).
__global__ void __launch_bounds__(256) k_top3(
    const float4* __restrict__ binnedBox, const int* __restrict__ binnedIdx,
    const float4* __restrict__ gt, const u32* __restrict__ cellStart,
    u64* __restrict__ partial3, int M)
{
    const int s    = blockIdx.x;
    const int m    = blockIdx.y;
    const int tid  = threadIdx.x;
    const int lane = tid & 63;
    const int w    = tid >> 6;

    float4 g = gt[m];
    float area_g = (g.z - g.x) * (g.w - g.y);
    int clx, chx, cly, chy;
    gt_range(g, clx, chx, cly, chy);

    u64 t0 = 0x00000000FFFFFFFFULL;   // (iou=0, ~0)
    u64 t1 = 0x00000000FFFFFFFEULL;   // (iou=0, ~1)
    u64 t2 = 0x00000000FFFFFFFDULL;   // (iou=0, ~2)

    int q = 0;
    for (int iy = cly; iy <= chy; ++iy)
        for (int ix = clx; ix <= chx; ++ix, ++q) {
            if (q % NSTRIPE != s) continue;
            int c = iy * NCX + ix;
            int cs = (int)cellStart[c];
            int ce = (int)cellStart[c + 1];
            for (int p = cs + tid; p < ce; p += 256) {
                float4 a = binnedBox[p];
                int  idx = binnedIdx[p];
                float area_a = (a.z - a.x) * (a.w - a.y);
                float inter, iou;
                IOU_EVAL(a, area_a, g, area_g, inter, iou);
                if (inter > 0.0f) {
                    u64 key = ((u64)__float_as_uint(iou) << 32) | (~(u32)idx);
                    INS3(t0, t1, t2, key);
                }
            }
        }

    for (int off = 1; off < 64; off <<= 1) {
        u64 o0 = shfl_xor_u64(t0, off);
        u64 o1 = shfl_xor_u64(t1, off);
        u64 o2 = shfl_xor_u64(t2, off);
        INS3(t0, t1, t2, o0);
        INS3(t0, t1, t2, o1);
        INS3(t0, t1, t2, o2);
    }

    __shared__ u64 s_red[4][3];
    if (lane == 0) { s_red[w][0] = t0; s_red[w][1] = t1; s_red[w][2] = t2; }
    __syncthreads();
    if (tid == 0) {
        u64 q0 = 0, q1 = 0, q2 = 0;
        for (int wv = 0; wv < 4; ++wv) {
            INS3(q0, q1, q2, s_red[wv][0]);
            INS3(q0, q1, q2, s_red[wv][1]);
            INS3(q0, q1, q2, s_red[wv][2]);
        }
        size_t b = ((size_t)m * NSTRIPE + s) * 3;
        partial3[b + 0] = q0;
        partial3[b + 1] = q1;
        partial3[b + 2] = q2;
    }
}

// ---------------------------------------------------------------------------
// Claims: merge stripe partials, then forced-claim scatter-max (break-free).
// claim key = (anchor<<32)|(gt+1); winner = max key among same-anchor claims.
__global__ void __launch_bounds__(256) k_claims(
    const u64* __restrict__ partial3, int* __restrict__ out, int M)
{
    __shared__ u64 s_key[3 * MPAD];
    const int tid = threadIdx.x;

    if (tid < M) {
        u64 q0 = 0, q1 = 0, q2 = 0;
        const u64* p = partial3 + (size_t)tid * NSTRIPE * 3;
        for (int c = 0; c < NSTRIPE * 3; ++c) INS3(q0, q1, q2, p[c]);

        float v0 = __uint_as_float((u32)(q0 >> 32));
        float v1 = __uint_as_float((u32)(q1 >> 32));
        float v2 = __uint_as_float((u32)(q2 >> 32));
        u32 a0 = ~(u32)q0;
        u32 a1 = ~(u32)q1;
        u32 a2 = ~(u32)q2;

        int npos = (v0 > POS_THRESH) + (v1 > POS_THRESH) + (v2 > POS_THRESH);
        bool low = npos < 3;

        s_key[tid * 3 + 0] = ((u64)a0 << 32) | (u32)(tid + 1);   // k==0 forced
        s_key[tid * 3 + 1] = (low && v1 > CLAIM_THRESH)
            ? (((u64)a1 << 32) | (u32)(tid + 1)) : 0ULL;
        s_key[tid * 3 + 2] = (low && v2 > CLAIM_THRESH)
            ? (((u64)a2 << 32) | (u32)(tid + 1)) : 0ULL;
    }
    __syncthreads();

    const int tote = 3 * M;
    for (int e = tid; e < tote; e += 256) {
        u64 my = s_key[e];
        if (my == 0) continue;
        u32 myA = (u32)(my >> 32);
        u64 mx = 0;
        for (int f = 0; f < tote; ++f) {          // break-free: pipelineable
            u64 k = s_key[f];
            bool same = (u32)(k >> 32) == myA;
            if (same && k > mx) mx = k;
        }
        if (mx == my) out[myA] = (int)(my & 0xffffffffULL) - 1;
    }
}

// ---------------------------------------------------------------------------
extern "C" void kernel_launch(void* const* d_in, const int* in_sizes, int n_in,
                              void* d_out, int out_size, void* d_ws, size_t ws_size,
                              hipStream_t stream) {
    const float4* anchor = (const float4*)d_in[0];
    const float4* gt     = (const float4*)d_in[1];
    int N = in_sizes[0] / 4;
    int M = in_sizes[1] / 4;
    int* out = (int*)d_out;

    // workspace layout (~10.53 MB for N=500k, M=200; <= proven 10.61 MB)
    char* ws = (char*)d_ws;
    size_t off = 0;
    auto alloc = [&](size_t bytes, size_t align) -> void* {
        off = (off + align - 1) / align * align;
        void* p = ws + off;
        off += bytes;
        return p;
    };
    u32* ccPad      = (u32*)alloc((size_t)NCELL * CPAD * 4, 64);
    u32* cellStart  = (u32*)alloc((NCELL + 1) * 4, 4);
    u32* gtCnt      = (u32*)alloc(NCELL * 4, 4);
    u64* partial3   = (u64*)alloc((size_t)M * NSTRIPE * 3 * 8, 8);
    u16* gtIds      = (u16*)alloc((size_t)NCELL * M * 2, 2);
    float4* binnedBox = (float4*)alloc((size_t)N * 16, 16);
    int* binnedIdx    = (int*)alloc((size_t)N * 4, 4);

    int nb = (N + 255) / 256;
    hipMemsetAsync(ccPad, 0, (size_t)NCELL * CPAD * 4, stream);
    k_hist<<<128, 256, 0, stream>>>(anchor, ccPad, N);
    k_scan<<<1, 256, 0, stream>>>(ccPad, cellStart, gt, gtCnt, gtIds, M);
    k_scatter<<<nb, 256, 0, stream>>>(anchor, ccPad, binnedBox, binnedIdx, N);
    k_assign<<<nb, 256, 0, stream>>>(binnedBox, binnedIdx, gt, gtCnt, gtIds,
                                     out, N, M);
    k_top3<<<dim3(NSTRIPE, M), 256, 0, stream>>>(binnedBox, binnedIdx, gt,
                                                 cellStart, partial3, M);
    k_claims<<<1, 256, 0, stream>>>(partial3, out, M);
}

// Round 11
// 121.269 us; speedup vs baseline: 2.6579x; 1.3332x over previous
//
#include <hip/hip_runtime.h>
#include <stdint.h>

// S3FD anchor assignment — spatially-binned exact rewrite, round 11.
// d_in[0]: anchor [N,4] f32, d_in[1]: gt [M,4] f32. d_out: assign [N] int32.
//
// Round 10 post-mortem: k_claims 54 us — the O(K^2) break-free winner scan
// (1800 LDS u64 reads/thread, single block) was latency-bound at ~72 cy/iter.
// Round 11: scatter-max done natively with a 1024-slot LDS hash table
// (tag = anchor+1 via atomicCAS, value = max claim key via 64-bit LDS
// atomicMax). ~600 inserts + ~600 lookups; winner unique per anchor.
// All other kernels byte-identical to the passing round-10 code.
//
// Key encoding (exact jax semantics), per-GT top-3:
//   key = (iou_bits << 32) | ~anchor_idx    (stable top_k: higher iou, then
//                                            lower anchor index wins)
// Zero-iou seed keys (0,~0),(0,~1),(0,~2) reproduce the reference's
// index-ordered zero fill; duplicated seeds across stripes are benign (they
// only surface when the corresponding claim dies on the > 0.1 gate; the
// all-zero case yields anchor 0 == reference ranks[m,0]).

typedef unsigned int u32;
typedef unsigned short u16;
typedef unsigned long long u64;

#define POS_THRESH 0.5f
#define NEG_THRESH 0.3f
#define CLAIM_THRESH 0.1f

constexpr int NCX = 32, NCY = 32, NCELL = NCX * NCY;  // 32x32 cells, 32 px
constexpr float INV_CELL = 0.03125f;                  // 1/32
constexpr float MARGIN = 64.5f;   // max anchor half-extent (<64.001) + slack
constexpr int MPAD = 256;         // padded GT count (M = 200)
constexpr int NSTRIPE = 10;       // k_top3 stripes per GT
constexpr int CPAD = 16;          // u32 stride per counter = one 64B line
constexpr int HSLOTS = 1024;      // claims hash table slots

#define INS3(t0, t1, t2, k) do {                                  \
    if ((k) > (t2)) {                                             \
        if ((k) > (t0))      { t2 = t1; t1 = t0; t0 = (k); }      \
        else if ((k) > (t1)) { t2 = t1; t1 = (k); }               \
        else                 { t2 = (k); }                        \
    } } while (0)

// IoU expression verbatim from the passing rounds (numpy-exact).
#define IOU_EVAL(a, areaA, g, areaG, inter, iou) {                \
    float ltx = fmaxf(a.x, g.x), lty = fmaxf(a.y, g.y);           \
    float rbx = fminf(a.z, g.z), rby = fminf(a.w, g.w);           \
    float ww = fmaxf(rbx - ltx, 0.0f);                            \
    float hh = fmaxf(rby - lty, 0.0f);                            \
    inter = ww * hh;                                              \
    iou = 0.0f;                                                   \
    if (inter > 0.0f) iou = inter / ((areaA + areaG) - inter);    \
}

__device__ __forceinline__ u64 shfl_xor_u64(u64 x, int mask) {
    int lo = __shfl_xor((int)(u32)x, mask, 64);
    int hi = __shfl_xor((int)(u32)(x >> 32), mask, 64);
    return ((u64)(u32)hi << 32) | (u32)lo;
}

__device__ __forceinline__ int cell_of(const float4 a) {
    float cx = 0.5f * (a.x + a.z);
    float cy = 0.5f * (a.y + a.w);
    int ix = (int)(cx * INV_CELL);
    int iy = (int)(cy * INV_CELL);
    ix = ix < 0 ? 0 : (ix > NCX - 1 ? NCX - 1 : ix);
    iy = iy < 0 ? 0 : (iy > NCY - 1 ? NCY - 1 : iy);
    return iy * NCX + ix;
}

__device__ __forceinline__ void gt_range(const float4 g, int& clx, int& chx,
                                         int& cly, int& chy) {
    clx = (int)floorf((g.x - MARGIN) * INV_CELL);
    chx = (int)floorf((g.z + MARGIN) * INV_CELL);
    cly = (int)floorf((g.y - MARGIN) * INV_CELL);
    chy = (int)floorf((g.w + MARGIN) * INV_CELL);
    clx = clx < 0 ? 0 : (clx > NCX - 1 ? NCX - 1 : clx);
    chx = chx < 0 ? 0 : (chx > NCX - 1 ? NCX - 1 : chx);
    cly = cly < 0 ? 0 : (cly > NCY - 1 ? NCY - 1 : cly);
    chy = chy < 0 ? 0 : (chy > NCY - 1 ? NCY - 1 : chy);
}

// ---------------------------------------------------------------------------
// Histogram anchors per cell (LDS-aggregated; padded global counters).
__global__ void __launch_bounds__(256) k_hist(
    const float4* __restrict__ anchor, u32* __restrict__ ccPad, int N)
{
    __shared__ u32 h[NCELL];
    const int tid = threadIdx.x;
    for (int c = tid; c < NCELL; c += 256) h[c] = 0;
    __syncthreads();
    for (int i = blockIdx.x * 256 + tid; i < N; i += 256 * gridDim.x)
        atomicAdd(&h[cell_of(anchor[i])], 1u);
    __syncthreads();
    for (int c = tid; c < NCELL; c += 256)
        if (h[c]) atomicAdd(&ccPad[c * CPAD], h[c]);
}

// ---------------------------------------------------------------------------
// Parallel exclusive scan (Hillis-Steele, 4 cells/thread); writes dense
// cellStart and rewrites ccPad in-place count -> cursor. Also builds per-cell
// GT lists (LDS-atomic slots; order nondeterministic, consumers are
// order-independent key-maxes).
__global__ void __launch_bounds__(256) k_scan(
    u32* __restrict__ ccPad, u32* __restrict__ cellStart,
    const float4* __restrict__ gt,
    u32* __restrict__ gtCnt, u16* __restrict__ gtIds, int M)
{
    __shared__ u32 s_sum[256];
    __shared__ u32 l_cnt[NCELL];
    const int tid = threadIdx.x;

    u32 c0 = ccPad[(tid * 4 + 0) * CPAD];
    u32 c1 = ccPad[(tid * 4 + 1) * CPAD];
    u32 c2 = ccPad[(tid * 4 + 2) * CPAD];
    u32 c3 = ccPad[(tid * 4 + 3) * CPAD];
    s_sum[tid] = c0 + c1 + c2 + c3;
    for (int c = tid; c < NCELL; c += 256) l_cnt[c] = 0;
    __syncthreads();

    for (int off = 1; off < 256; off <<= 1) {
        u32 v = (tid >= off) ? s_sum[tid - off] : 0;
        __syncthreads();
        s_sum[tid] += v;
        __syncthreads();
    }

    u32 base = tid ? s_sum[tid - 1] : 0;
    cellStart[tid * 4 + 0] = base;  ccPad[(tid * 4 + 0) * CPAD] = base;
    base += c0;
    cellStart[tid * 4 + 1] = base;  ccPad[(tid * 4 + 1) * CPAD] = base;
    base += c1;
    cellStart[tid * 4 + 2] = base;  ccPad[(tid * 4 + 2) * CPAD] = base;
    base += c2;
    cellStart[tid * 4 + 3] = base;  ccPad[(tid * 4 + 3) * CPAD] = base;
    if (tid == 255) cellStart[NCELL] = s_sum[255];

    if (tid < M) {
        float4 g = gt[tid];
        int clx, chx, cly, chy;
        gt_range(g, clx, chx, cly, chy);
        for (int iy = cly; iy <= chy; ++iy)
            for (int ix = clx; ix <= chx; ++ix) {
                int c = iy * NCX + ix;
                u32 slot = atomicAdd(&l_cnt[c], 1u);
                gtIds[(size_t)c * M + slot] = (u16)tid;
            }
    }
    __syncthreads();
    for (int c = tid; c < NCELL; c += 256) gtCnt[c] = l_cnt[c];
}

// ---------------------------------------------------------------------------
// Scatter anchors into cell-binned order (padded cursors: 1 line per cell).
__global__ void __launch_bounds__(256) k_scatter(
    const float4* __restrict__ anchor, u32* __restrict__ ccPad,
    float4* __restrict__ binnedBox, int* __restrict__ binnedIdx, int N)
{
    int i = blockIdx.x * 256 + threadIdx.x;
    if (i >= N) return;
    float4 a = anchor[i];
    u32 pos = atomicAdd(&ccPad[cell_of(a) * CPAD], 1u);
    binnedBox[pos] = a;
    binnedIdx[pos] = i;
}

// ---------------------------------------------------------------------------
// Base assignment: each binned anchor vs its cell's GT list (uniform cnt
// within a block since binned order groups same-cell anchors).
__global__ void __launch_bounds__(256) k_assign(
    const float4* __restrict__ binnedBox, const int* __restrict__ binnedIdx,
    const float4* __restrict__ gt, const u32* __restrict__ gtCnt,
    const u16* __restrict__ gtIds, int* __restrict__ out, int N, int M)
{
    __shared__ float4 s_g[MPAD];
    __shared__ float  s_ga[MPAD];
    const int tid = threadIdx.x;
    if (tid < M) {
        float4 g = gt[tid];
        s_g[tid]  = g;
        s_ga[tid] = (g.z - g.x) * (g.w - g.y);
    }
    __syncthreads();

    int p = blockIdx.x * 256 + tid;
    if (p >= N) return;
    float4 a  = binnedBox[p];
    int   idx = binnedIdx[p];
    float area_a = (a.z - a.x) * (a.w - a.y);
    int c   = cell_of(a);
    int cnt = (int)gtCnt[c];
    const u16* list = gtIds + (size_t)c * M;

    u64 best = 0;
    for (int k = 0; k < cnt; ++k) {
        int m = list[k];
        float4 g = s_g[m];
        float inter, iou;
        IOU_EVAL(a, area_a, g, s_ga[m], inter, iou);
        if (inter > 0.0f) {
            u64 key = ((u64)__float_as_uint(iou) << 32) | (~(u32)m);
            best = key > best ? key : best;
        }
    }
    u32 ib = (u32)(best >> 32);
    int v = -2;
    if (ib < __float_as_uint(NEG_THRESH)) v = -1;   // max iou < 0.3 (incl 0)
    if (ib > __float_as_uint(POS_THRESH)) v = (int)(~(u32)best);
    out[idx] = v;
}

// ---------------------------------------------------------------------------
// Per-GT top-3, striped: grid (NSTRIPE, M) x 256. Block (s,m) takes every
// NSTRIPE-th covered cell of GT m; writes stripe partial (3 u64).
__global__ void __launch_bounds__(256) k_top3(
    const float4* __restrict__ binnedBox, const int* __restrict__ binnedIdx,
    const float4* __restrict__ gt, const u32* __restrict__ cellStart,
    u64* __restrict__ partial3, int M)
{
    const int s    = blockIdx.x;
    const int m    = blockIdx.y;
    const int tid  = threadIdx.x;
    const int lane = tid & 63;
    const int w    = tid >> 6;

    float4 g = gt[m];
    float area_g = (g.z - g.x) * (g.w - g.y);
    int clx, chx, cly, chy;
    gt_range(g, clx, chx, cly, chy);

    u64 t0 = 0x00000000FFFFFFFFULL;   // (iou=0, ~0)
    u64 t1 = 0x00000000FFFFFFFEULL;   // (iou=0, ~1)
    u64 t2 = 0x00000000FFFFFFFDULL;   // (iou=0, ~2)

    int q = 0;
    for (int iy = cly; iy <= chy; ++iy)
        for (int ix = clx; ix <= chx; ++ix, ++q) {
            if (q % NSTRIPE != s) continue;
            int c = iy * NCX + ix;
            int cs = (int)cellStart[c];
            int ce = (int)cellStart[c + 1];
            for (int p = cs + tid; p < ce; p += 256) {
                float4 a = binnedBox[p];
                int  idx = binnedIdx[p];
                float area_a = (a.z - a.x) * (a.w - a.y);
                float inter, iou;
                IOU_EVAL(a, area_a, g, area_g, inter, iou);
                if (inter > 0.0f) {
                    u64 key = ((u64)__float_as_uint(iou) << 32) | (~(u32)idx);
                    INS3(t0, t1, t2, key);
                }
            }
        }

    for (int off = 1; off < 64; off <<= 1) {
        u64 o0 = shfl_xor_u64(t0, off);
        u64 o1 = shfl_xor_u64(t1, off);
        u64 o2 = shfl_xor_u64(t2, off);
        INS3(t0, t1, t2, o0);
        INS3(t0, t1, t2, o1);
        INS3(t0, t1, t2, o2);
    }

    __shared__ u64 s_red[4][3];
    if (lane == 0) { s_red[w][0] = t0; s_red[w][1] = t1; s_red[w][2] = t2; }
    __syncthreads();
    if (tid == 0) {
        u64 q0 = 0, q1 = 0, q2 = 0;
        for (int wv = 0; wv < 4; ++wv) {
            INS3(q0, q1, q2, s_red[wv][0]);
            INS3(q0, q1, q2, s_red[wv][1]);
            INS3(q0, q1, q2, s_red[wv][2]);
        }
        size_t b = ((size_t)m * NSTRIPE + s) * 3;
        partial3[b + 0] = q0;
        partial3[b + 1] = q1;
        partial3[b + 2] = q2;
    }
}

// ---------------------------------------------------------------------------
// Claims: merge stripe partials, then forced-claim scatter-max via a 1024-
// slot LDS hash table (tag = anchor+1 via atomicCAS, value = 64-bit LDS
// atomicMax of claim key). Winner (unique per anchor) writes out[].
// claim key = (anchor<<32)|(gt+1); max key == last-writer gt == reference.
__global__ void __launch_bounds__(256) k_claims(
    const u64* __restrict__ partial3, int* __restrict__ out, int M)
{
    __shared__ u64 s_key[3 * MPAD];
    __shared__ u64 h_val[HSLOTS];
    __shared__ u32 h_tag[HSLOTS];   // anchor+1; 0 = empty
    const int tid = threadIdx.x;

    for (int i = tid; i < HSLOTS; i += 256) { h_val[i] = 0; h_tag[i] = 0; }

    if (tid < M) {
        u64 q0 = 0, q1 = 0, q2 = 0;
        const u64* p = partial3 + (size_t)tid * NSTRIPE * 3;
        for (int c = 0; c < NSTRIPE * 3; ++c) INS3(q0, q1, q2, p[c]);

        float v0 = __uint_as_float((u32)(q0 >> 32));
        float v1 = __uint_as_float((u32)(q1 >> 32));
        float v2 = __uint_as_float((u32)(q2 >> 32));
        u32 a0 = ~(u32)q0;
        u32 a1 = ~(u32)q1;
        u32 a2 = ~(u32)q2;

        int npos = (v0 > POS_THRESH) + (v1 > POS_THRESH) + (v2 > POS_THRESH);
        bool low = npos < 3;

        s_key[tid * 3 + 0] = ((u64)a0 << 32) | (u32)(tid + 1);   // k==0 forced
        s_key[tid * 3 + 1] = (low && v1 > CLAIM_THRESH)
            ? (((u64)a1 << 32) | (u32)(tid + 1)) : 0ULL;
        s_key[tid * 3 + 2] = (low && v2 > CLAIM_THRESH)
            ? (((u64)a2 << 32) | (u32)(tid + 1)) : 0ULL;
    }
    __syncthreads();

    const int tote = 3 * M;
    // insert: claim slot by anchor tag, atomicMax the claim key
    for (int e = tid; e < tote; e += 256) {
        u64 my = s_key[e];
        if (my == 0) continue;
        u32 myA = (u32)(my >> 32);
        u32 slot = (myA * 2654435761u) & (HSLOTS - 1);
        while (true) {
            u32 prev = atomicCAS(&h_tag[slot], 0u, myA + 1u);
            if (prev == 0u || prev == myA + 1u) {
                atomicMax(&h_val[slot], my);
                break;
            }
            slot = (slot + 1) & (HSLOTS - 1);
        }
    }
    __syncthreads();
    // resolve: claim wins iff it holds the max key for its anchor
    for (int e = tid; e < tote; e += 256) {
        u64 my = s_key[e];
        if (my == 0) continue;
        u32 myA = (u32)(my >> 32);
        u32 slot = (myA * 2654435761u) & (HSLOTS - 1);
        while (h_tag[slot] != myA + 1u) slot = (slot + 1) & (HSLOTS - 1);
        if (h_val[slot] == my) out[myA] = (int)(my & 0xffffffffULL) - 1;
    }
}

// ---------------------------------------------------------------------------
extern "C" void kernel_launch(void* const* d_in, const int* in_sizes, int n_in,
                              void* d_out, int out_size, void* d_ws, size_t ws_size,
                              hipStream_t stream) {
    const float4* anchor = (const float4*)d_in[0];
    const float4* gt     = (const float4*)d_in[1];
    int N = in_sizes[0] / 4;
    int M = in_sizes[1] / 4;
    int* out = (int*)d_out;

    // workspace layout (~10.53 MB for N=500k, M=200; <= proven 10.61 MB)
    char* ws = (char*)d_ws;
    size_t off = 0;
    auto alloc = [&](size_t bytes, size_t align) -> void* {
        off = (off + align - 1) / align * align;
        void* p = ws + off;
        off += bytes;
        return p;
    };
    u32* ccPad      = (u32*)alloc((size_t)NCELL * CPAD * 4, 64);
    u32* cellStart  = (u32*)alloc((NCELL + 1) * 4, 4);
    u32* gtCnt      = (u32*)alloc(NCELL * 4, 4);
    u64* partial3   = (u64*)alloc((size_t)M * NSTRIPE * 3 * 8, 8);
    u16* gtIds      = (u16*)alloc((size_t)NCELL * M * 2, 2);
    float4* binnedBox = (float4*)alloc((size_t)N * 16, 16);
    int* binnedIdx    = (int*)alloc((size_t)N * 4, 4);

    int nb = (N + 255) / 256;
    hipMemsetAsync(ccPad, 0, (size_t)NCELL * CPAD * 4, stream);
    k_hist<<<128, 256, 0, stream>>>(anchor, ccPad, N);
    k_scan<<<1, 256, 0, stream>>>(ccPad, cellStart, gt, gtCnt, gtIds, M);
    k_scatter<<<nb, 256, 0, stream>>>(anchor, ccPad, binnedBox, binnedIdx, N);
    k_assign<<<nb, 256, 0, stream>>>(binnedBox, binnedIdx, gt, gtCnt, gtIds,
                                     out, N, M);
    k_top3<<<dim3(NSTRIPE, M), 256, 0, stream>>>(binnedBox, binnedIdx, gt,
                                                 cellStart, partial3, M);
    k_claims<<<1, 256, 0, stream>>>(partial3, out, M);
}

// Round 12
// 117.080 us; speedup vs baseline: 2.7530x; 1.0358x over previous
//
#include <hip/hip_runtime.h>
#include <stdint.h>

// S3FD anchor assignment — spatially-binned exact rewrite, round 12.
// d_in[0]: anchor [N,4] f32, d_in[1]: gt [M,4] f32. d_out: assign [N] int32.
//
// Round 11 post-mortem: the hipMemsetAsync(ccPad) fill dispatch cost ~43 us
// inside the captured graph (top-5 was all fillBufferAligned). Also learned
// ws_size ~= 256 MB (harness poison fill). Round 12: no memset — k_hist is
// atomic-free, writing per-block LDS histograms to histPart[128][1024]
// (plain stores, no init needed); k_scan sums the partials then does the
// unchanged scan/cursor/GT-list work. All other kernels byte-identical to
// the passing round-11 code.
//
// Key encoding (exact jax semantics), per-GT top-3:
//   key = (iou_bits << 32) | ~anchor_idx    (stable top_k: higher iou, then
//                                            lower anchor index wins)
// Zero-iou seed keys (0,~0),(0,~1),(0,~2) reproduce the reference's
// index-ordered zero fill; duplicated seeds across stripes are benign.

typedef unsigned int u32;
typedef unsigned short u16;
typedef unsigned long long u64;

#define POS_THRESH 0.5f
#define NEG_THRESH 0.3f
#define CLAIM_THRESH 0.1f

constexpr int NCX = 32, NCY = 32, NCELL = NCX * NCY;  // 32x32 cells, 32 px
constexpr float INV_CELL = 0.03125f;                  // 1/32
constexpr float MARGIN = 64.5f;   // max anchor half-extent (<64.001) + slack
constexpr int MPAD = 256;         // padded GT count (M = 200)
constexpr int NSTRIPE = 10;       // k_top3 stripes per GT
constexpr int CPAD = 16;          // u32 stride per counter = one 64B line
constexpr int HSLOTS = 1024;      // claims hash table slots
constexpr int HB = 128;           // k_hist blocks

#define INS3(t0, t1, t2, k) do {                                  \
    if ((k) > (t2)) {                                             \
        if ((k) > (t0))      { t2 = t1; t1 = t0; t0 = (k); }      \
        else if ((k) > (t1)) { t2 = t1; t1 = (k); }               \
        else                 { t2 = (k); }                        \
    } } while (0)

// IoU expression verbatim from the passing rounds (numpy-exact).
#define IOU_EVAL(a, areaA, g, areaG, inter, iou) {                \
    float ltx = fmaxf(a.x, g.x), lty = fmaxf(a.y, g.y);           \
    float rbx = fminf(a.z, g.z), rby = fminf(a.w, g.w);           \
    float ww = fmaxf(rbx - ltx, 0.0f);                            \
    float hh = fmaxf(rby - lty, 0.0f);                            \
    inter = ww * hh;                                              \
    iou = 0.0f;                                                   \
    if (inter > 0.0f) iou = inter / ((areaA + areaG) - inter);    \
}

__device__ __forceinline__ u64 shfl_xor_u64(u64 x, int mask) {
    int lo = __shfl_xor((int)(u32)x, mask, 64);
    int hi = __shfl_xor((int)(u32)(x >> 32), mask, 64);
    return ((u64)(u32)hi << 32) | (u32)lo;
}

__device__ __forceinline__ int cell_of(const float4 a) {
    float cx = 0.5f * (a.x + a.z);
    float cy = 0.5f * (a.y + a.w);
    int ix = (int)(cx * INV_CELL);
    int iy = (int)(cy * INV_CELL);
    ix = ix < 0 ? 0 : (ix > NCX - 1 ? NCX - 1 : ix);
    iy = iy < 0 ? 0 : (iy > NCY - 1 ? NCY - 1 : iy);
    return iy * NCX + ix;
}

__device__ __forceinline__ void gt_range(const float4 g, int& clx, int& chx,
                                         int& cly, int& chy) {
    clx = (int)floorf((g.x - MARGIN) * INV_CELL);
    chx = (int)floorf((g.z + MARGIN) * INV_CELL);
    cly = (int)floorf((g.y - MARGIN) * INV_CELL);
    chy = (int)floorf((g.w + MARGIN) * INV_CELL);
    clx = clx < 0 ? 0 : (clx > NCX - 1 ? NCX - 1 : clx);
    chx = chx < 0 ? 0 : (chx > NCX - 1 ? NCX - 1 : chx);
    cly = cly < 0 ? 0 : (cly > NCY - 1 ? NCY - 1 : cly);
    chy = chy < 0 ? 0 : (chy > NCY - 1 ? NCY - 1 : chy);
}

// ---------------------------------------------------------------------------
// Histogram anchors per cell: per-block LDS histogram -> dense partial slab.
// No global atomics, no pre-zeroed global memory needed.
__global__ void __launch_bounds__(256) k_hist(
    const float4* __restrict__ anchor, u32* __restrict__ histPart, int N)
{
    __shared__ u32 h[NCELL];
    const int tid = threadIdx.x;
    for (int c = tid; c < NCELL; c += 256) h[c] = 0;
    __syncthreads();
    for (int i = blockIdx.x * 256 + tid; i < N; i += 256 * HB)
        atomicAdd(&h[cell_of(anchor[i])], 1u);
    __syncthreads();
    u32* mine = histPart + (size_t)blockIdx.x * NCELL;
    for (int c = tid; c < NCELL; c += 256) mine[c] = h[c];
}

// ---------------------------------------------------------------------------
// Sum hist partials -> counts; Hillis-Steele exclusive scan (4 cells/thread);
// write dense cellStart + padded cursors; build per-cell GT lists.
__global__ void __launch_bounds__(256) k_scan(
    const u32* __restrict__ histPart, u32* __restrict__ ccPad,
    u32* __restrict__ cellStart, const float4* __restrict__ gt,
    u32* __restrict__ gtCnt, u16* __restrict__ gtIds, int M)
{
    __shared__ u32 s_sum[256];
    __shared__ u32 l_cnt[NCELL];
    const int tid = threadIdx.x;

    u32 c0 = 0, c1 = 0, c2 = 0, c3 = 0;
    for (int b = 0; b < HB; ++b) {
        const u32* p = histPart + (size_t)b * NCELL + tid * 4;
        c0 += p[0]; c1 += p[1]; c2 += p[2]; c3 += p[3];
    }
    s_sum[tid] = c0 + c1 + c2 + c3;
    for (int c = tid; c < NCELL; c += 256) l_cnt[c] = 0;
    __syncthreads();

    for (int off = 1; off < 256; off <<= 1) {
        u32 v = (tid >= off) ? s_sum[tid - off] : 0;
        __syncthreads();
        s_sum[tid] += v;
        __syncthreads();
    }

    u32 base = tid ? s_sum[tid - 1] : 0;
    cellStart[tid * 4 + 0] = base;  ccPad[(tid * 4 + 0) * CPAD] = base;
    base += c0;
    cellStart[tid * 4 + 1] = base;  ccPad[(tid * 4 + 1) * CPAD] = base;
    base += c1;
    cellStart[tid * 4 + 2] = base;  ccPad[(tid * 4 + 2) * CPAD] = base;
    base += c2;
    cellStart[tid * 4 + 3] = base;  ccPad[(tid * 4 + 3) * CPAD] = base;
    if (tid == 255) cellStart[NCELL] = s_sum[255];

    if (tid < M) {
        float4 g = gt[tid];
        int clx, chx, cly, chy;
        gt_range(g, clx, chx, cly, chy);
        for (int iy = cly; iy <= chy; ++iy)
            for (int ix = clx; ix <= chx; ++ix) {
                int c = iy * NCX + ix;
                u32 slot = atomicAdd(&l_cnt[c], 1u);
                gtIds[(size_t)c * M + slot] = (u16)tid;
            }
    }
    __syncthreads();
    for (int c = tid; c < NCELL; c += 256) gtCnt[c] = l_cnt[c];
}

// ---------------------------------------------------------------------------
// Scatter anchors into cell-binned order (padded cursors: 1 line per cell).
__global__ void __launch_bounds__(256) k_scatter(
    const float4* __restrict__ anchor, u32* __restrict__ ccPad,
    float4* __restrict__ binnedBox, int* __restrict__ binnedIdx, int N)
{
    int i = blockIdx.x * 256 + threadIdx.x;
    if (i >= N) return;
    float4 a = anchor[i];
    u32 pos = atomicAdd(&ccPad[cell_of(a) * CPAD], 1u);
    binnedBox[pos] = a;
    binnedIdx[pos] = i;
}

// ---------------------------------------------------------------------------
// Base assignment: each binned anchor vs its cell's GT list (uniform cnt
// within a block since binned order groups same-cell anchors).
__global__ void __launch_bounds__(256) k_assign(
    const float4* __restrict__ binnedBox, const int* __restrict__ binnedIdx,
    const float4* __restrict__ gt, const u32* __restrict__ gtCnt,
    const u16* __restrict__ gtIds, int* __restrict__ out, int N, int M)
{
    __shared__ float4 s_g[MPAD];
    __shared__ float  s_ga[MPAD];
    const int tid = threadIdx.x;
    if (tid < M) {
        float4 g = gt[tid];
        s_g[tid]  = g;
        s_ga[tid] = (g.z - g.x) * (g.w - g.y);
    }
    __syncthreads();

    int p = blockIdx.x * 256 + tid;
    if (p >= N) return;
    float4 a  = binnedBox[p];
    int   idx = binnedIdx[p];
    float area_a = (a.z - a.x) * (a.w - a.y);
    int c   = cell_of(a);
    int cnt = (int)gtCnt[c];
    const u16* list = gtIds + (size_t)c * M;

    u64 best = 0;
    for (int k = 0; k < cnt; ++k) {
        int m = list[k];
        float4 g = s_g[m];
        float inter, iou;
        IOU_EVAL(a, area_a, g, s_ga[m], inter, iou);
        if (inter > 0.0f) {
            u64 key = ((u64)__float_as_uint(iou) << 32) | (~(u32)m);
            best = key > best ? key : best;
        }
    }
    u32 ib = (u32)(best >> 32);
    int v = -2;
    if (ib < __float_as_uint(NEG_THRESH)) v = -1;   // max iou < 0.3 (incl 0)
    if (ib > __float_as_uint(POS_THRESH)) v = (int)(~(u32)best);
    out[idx] = v;
}

// ---------------------------------------------------------------------------
// Per-GT top-3, striped: grid (NSTRIPE, M) x 256. Block (s,m) takes every
// NSTRIPE-th covered cell of GT m; writes stripe partial (3 u64).
__global__ void __launch_bounds__(256) k_top3(
    const float4* __restrict__ binnedBox, const int* __restrict__ binnedIdx,
    const float4* __restrict__ gt, const u32* __restrict__ cellStart,
    u64* __restrict__ partial3, int M)
{
    const int s    = blockIdx.x;
    const int m    = blockIdx.y;
    const int tid  = threadIdx.x;
    const int lane = tid & 63;
    const int w    = tid >> 6;

    float4 g = gt[m];
    float area_g = (g.z - g.x) * (g.w - g.y);
    int clx, chx, cly, chy;
    gt_range(g, clx, chx, cly, chy);

    u64 t0 = 0x00000000FFFFFFFFULL;   // (iou=0, ~0)
    u64 t1 = 0x00000000FFFFFFFEULL;   // (iou=0, ~1)
    u64 t2 = 0x00000000FFFFFFFDULL;   // (iou=0, ~2)

    int q = 0;
    for (int iy = cly; iy <= chy; ++iy)
        for (int ix = clx; ix <= chx; ++ix, ++q) {
            if (q % NSTRIPE != s) continue;
            int c = iy * NCX + ix;
            int cs = (int)cellStart[c];
            int ce = (int)cellStart[c + 1];
            for (int p = cs + tid; p < ce; p += 256) {
                float4 a = binnedBox[p];
                int  idx = binnedIdx[p];
                float area_a = (a.z - a.x) * (a.w - a.y);
                float inter, iou;
                IOU_EVAL(a, area_a, g, area_g, inter, iou);
                if (inter > 0.0f) {
                    u64 key = ((u64)__float_as_uint(iou) << 32) | (~(u32)idx);
                    INS3(t0, t1, t2, key);
                }
            }
        }

    for (int off = 1; off < 64; off <<= 1) {
        u64 o0 = shfl_xor_u64(t0, off);
        u64 o1 = shfl_xor_u64(t1, off);
        u64 o2 = shfl_xor_u64(t2, off);
        INS3(t0, t1, t2, o0);
        INS3(t0, t1, t2, o1);
        INS3(t0, t1, t2, o2);
    }

    __shared__ u64 s_red[4][3];
    if (lane == 0) { s_red[w][0] = t0; s_red[w][1] = t1; s_red[w][2] = t2; }
    __syncthreads();
    if (tid == 0) {
        u64 q0 = 0, q1 = 0, q2 = 0;
        for (int wv = 0; wv < 4; ++wv) {
            INS3(q0, q1, q2, s_red[wv][0]);
            INS3(q0, q1, q2, s_red[wv][1]);
            INS3(q0, q1, q2, s_red[wv][2]);
        }
        size_t b = ((size_t)m * NSTRIPE + s) * 3;
        partial3[b + 0] = q0;
        partial3[b + 1] = q1;
        partial3[b + 2] = q2;
    }
}

// ---------------------------------------------------------------------------
// Claims: merge stripe partials, then forced-claim scatter-max via a 1024-
// slot LDS hash table (tag = anchor+1 via atomicCAS, value = 64-bit LDS
// atomicMax of claim key). Winner (unique per anchor) writes out[].
// claim key = (anchor<<32)|(gt+1); max key == last-writer gt == reference.
__global__ void __launch_bounds__(256) k_claims(
    const u64* __restrict__ partial3, int* __restrict__ out, int M)
{
    __shared__ u64 s_key[3 * MPAD];
    __shared__ u64 h_val[HSLOTS];
    __shared__ u32 h_tag[HSLOTS];   // anchor+1; 0 = empty
    const int tid = threadIdx.x;

    for (int i = tid; i < HSLOTS; i += 256) { h_val[i] = 0; h_tag[i] = 0; }

    if (tid < M) {
        u64 q0 = 0, q1 = 0, q2 = 0;
        const u64* p = partial3 + (size_t)tid * NSTRIPE * 3;
        for (int c = 0; c < NSTRIPE * 3; ++c) INS3(q0, q1, q2, p[c]);

        float v0 = __uint_as_float((u32)(q0 >> 32));
        float v1 = __uint_as_float((u32)(q1 >> 32));
        float v2 = __uint_as_float((u32)(q2 >> 32));
        u32 a0 = ~(u32)q0;
        u32 a1 = ~(u32)q1;
        u32 a2 = ~(u32)q2;

        int npos = (v0 > POS_THRESH) + (v1 > POS_THRESH) + (v2 > POS_THRESH);
        bool low = npos < 3;

        s_key[tid * 3 + 0] = ((u64)a0 << 32) | (u32)(tid + 1);   // k==0 forced
        s_key[tid * 3 + 1] = (low && v1 > CLAIM_THRESH)
            ? (((u64)a1 << 32) | (u32)(tid + 1)) : 0ULL;
        s_key[tid * 3 + 2] = (low && v2 > CLAIM_THRESH)
            ? (((u64)a2 << 32) | (u32)(tid + 1)) : 0ULL;
    }
    __syncthreads();

    const int tote = 3 * M;
    // insert: claim slot by anchor tag, atomicMax the claim key
    for (int e = tid; e < tote; e += 256) {
        u64 my = s_key[e];
        if (my == 0) continue;
        u32 myA = (u32)(my >> 32);
        u32 slot = (myA * 2654435761u) & (HSLOTS - 1);
        while (true) {
            u32 prev = atomicCAS(&h_tag[slot], 0u, myA + 1u);
            if (prev == 0u || prev == myA + 1u) {
                atomicMax(&h_val[slot], my);
                break;
            }
            slot = (slot + 1) & (HSLOTS - 1);
        }
    }
    __syncthreads();
    // resolve: claim wins iff it holds the max key for its anchor
    for (int e = tid; e < tote; e += 256) {
        u64 my = s_key[e];
        if (my == 0) continue;
        u32 myA = (u32)(my >> 32);
        u32 slot = (myA * 2654435761u) & (HSLOTS - 1);
        while (h_tag[slot] != myA + 1u) slot = (slot + 1) & (HSLOTS - 1);
        if (h_val[slot] == my) out[myA] = (int)(my & 0xffffffffULL) - 1;
    }
}

// ---------------------------------------------------------------------------
extern "C" void kernel_launch(void* const* d_in, const int* in_sizes, int n_in,
                              void* d_out, int out_size, void* d_ws, size_t ws_size,
                              hipStream_t stream) {
    const float4* anchor = (const float4*)d_in[0];
    const float4* gt     = (const float4*)d_in[1];
    int N = in_sizes[0] / 4;
    int M = in_sizes[1] / 4;
    int* out = (int*)d_out;

    // workspace layout (~11.0 MB for N=500k, M=200; ws_size ~= 256 MB)
    char* ws = (char*)d_ws;
    size_t off = 0;
    auto alloc = [&](size_t bytes, size_t align) -> void* {
        off = (off + align - 1) / align * align;
        void* p = ws + off;
        off += bytes;
        return p;
    };
    u32* histPart   = (u32*)alloc((size_t)HB * NCELL * 4, 64);
    u32* ccPad      = (u32*)alloc((size_t)NCELL * CPAD * 4, 64);
    u32* cellStart  = (u32*)alloc((NCELL + 1) * 4, 4);
    u32* gtCnt      = (u32*)alloc(NCELL * 4, 4);
    u64* partial3   = (u64*)alloc((size_t)M * NSTRIPE * 3 * 8, 8);
    u16* gtIds      = (u16*)alloc((size_t)NCELL * M * 2, 2);
    float4* binnedBox = (float4*)alloc((size_t)N * 16, 16);
    int* binnedIdx    = (int*)alloc((size_t)N * 4, 4);

    int nb = (N + 255) / 256;
    k_hist<<<HB, 256, 0, stream>>>(anchor, histPart, N);
    k_scan<<<1, 256, 0, stream>>>(histPart, ccPad, cellStart, gt, gtCnt,
                                  gtIds, M);
    k_scatter<<<nb, 256, 0, stream>>>(anchor, ccPad, binnedBox, binnedIdx, N);
    k_assign<<<nb, 256, 0, stream>>>(binnedBox, binnedIdx, gt, gtCnt, gtIds,
                                     out, N, M);
    k_top3<<<dim3(NSTRIPE, M), 256, 0, stream>>>(binnedBox, binnedIdx, gt,
                                                 cellStart, partial3, M);
    k_claims<<<1, 256, 0, stream>>>(partial3, out, M);
}